// Round 4
// baseline (245.844 us; speedup 1.0000x reference)
//
#include <hip/hip_runtime.h>

// FlowUpSampler: flow [N,2,H,W], mask [N,576,H,W] -> out [N,2,8H,8W]
// N=8, H=64, W=128. q = k*64 + a*8 + b, k = di*3+dj (unfold order).
//
// R4: MEASUREMENT ROUND. Kernel is byte-identical to R3; we launch it TWICE
// (idempotent, serialized on `stream`). dur_us(R4) - dur_us(R3) = exact
// kernel execution time, separating kernel cost from the ~150-185 us of
// per-iteration harness restore/poison cost that rocprof shows
// (576 MiB fillBufferAligned @ ~90 us dominates the top-5).

#define N_ 8
#define H_ 64
#define W_ 128
#define HW_ (H_ * W_)

__global__ __launch_bounds__(256, 4) void flow_up_kernel(
    const float* __restrict__ flow,
    const float* __restrict__ mask,
    float* __restrict__ out)
{
    const int bid = blockIdx.x;
    const int a = bid & 7;
    const int h = (bid >> 3) & (H_ - 1);
    const int n = bid >> 9;
    const int t = threadIdx.x;
    const int b = t & 7;            // lane-minor: stores coalesce in 32B groups
    const int w4 = (t >> 3) << 2;   // 0,4,...,124

    // Halo rows r[c][di][j] = 8*flow_pad[n,c,h-1+di,w4-1+j], j=0..5, zero-padded.
    float r0[3][6], r1[3][6];
    const float* __restrict__ f0 = flow + (n * 2 + 0) * HW_;
    const float* __restrict__ f1 = flow + (n * 2 + 1) * HW_;
#pragma unroll
    for (int di = 0; di < 3; ++di) {
        const int hr = h - 1 + di;
        const int hc = min(max(hr, 0), H_ - 1);
        const bool hin = (hr >= 0) && (hr < H_);
#pragma unroll
        for (int j = 0; j < 6; ++j) {
            const int wr = w4 - 1 + j;
            const int wc = min(max(wr, 0), W_ - 1);
            const float sc = (hin && wr >= 0 && wr < W_) ? 8.0f : 0.0f;
            r0[di][j] = f0[hc * W_ + wc] * sc;
            r1[di][j] = f1[hc * W_ + wc] * sc;
        }
    }

    // mask float4 pointer at (n, a*8+b, h, w4); k stride = 64*HW_ floats = 16*HW_ float4
    const float4* __restrict__ mp =
        (const float4*)(mask + (n * 576 + a * 8 + b) * HW_ + h * W_ + w4);

    float ss[4] = {0.f, 0.f, 0.f, 0.f};
    float o0[4] = {0.f, 0.f, 0.f, 0.f};
    float o1[4] = {0.f, 0.f, 0.f, 0.f};
#pragma unroll
    for (int k = 0; k < 9; ++k) {
        const int di = k / 3, dj = k % 3;      // compile-time (unrolled)
        const float4 m = mp[k * 16 * HW_];
        const float e0 = __expf(m.x), e1 = __expf(m.y),
                    e2 = __expf(m.z), e3 = __expf(m.w);
        ss[0] += e0; o0[0] += e0 * r0[di][dj + 0]; o1[0] += e0 * r1[di][dj + 0];
        ss[1] += e1; o0[1] += e1 * r0[di][dj + 1]; o1[1] += e1 * r1[di][dj + 1];
        ss[2] += e2; o0[2] += e2 * r0[di][dj + 2]; o1[2] += e2 * r1[di][dj + 2];
        ss[3] += e3; o0[3] += e3 * r0[di][dj + 3]; o1[3] += e3 * r1[di][dj + 3];
    }

    const int y = h * 8 + a;
    float* __restrict__ q0 = out + ((n * 2 + 0) * (8 * H_) + y) * (8 * W_) + 8 * w4 + b;
    float* __restrict__ q1 = out + ((n * 2 + 1) * (8 * H_) + y) * (8 * W_) + 8 * w4 + b;
#pragma unroll
    for (int wi = 0; wi < 4; ++wi) {
        const float inv = __builtin_amdgcn_rcpf(ss[wi]);  // threshold 0.54, 1-ulp ok
        q0[8 * wi] = o0[wi] * inv;
        q1[8 * wi] = o1[wi] * inv;
    }
}

extern "C" void kernel_launch(void* const* d_in, const int* in_sizes, int n_in,
                              void* d_out, int out_size, void* d_ws, size_t ws_size,
                              hipStream_t stream) {
    const float* flow = (const float*)d_in[0];
    const float* mask = (const float*)d_in[1];
    float* out = (float*)d_out;

    const int grid = N_ * H_ * 8;   // 4096 blocks, one per (n, h, a)
    // Launched twice on purpose: idempotent, measures marginal kernel cost
    // against R3's single-launch dur_us.
    flow_up_kernel<<<grid, 256, 0, stream>>>(flow, mask, out);
    flow_up_kernel<<<grid, 256, 0, stream>>>(flow, mask, out);
}

// Round 5
// 220.631 us; speedup vs baseline: 1.1143x; 1.1143x over previous
//
#include <hip/hip_runtime.h>

// FlowUpSampler: flow [N,2,H,W], mask [N,576,H,W] -> out [N,2,8H,8W]
// N=8, H=64, W=128. q = k*64 + a*8 + b, k = di*3+dj (unfold order).
// out[n,c,8h+a,8w+b] = sum_k softmax_k(mask[n,k,a,b,h,w]) * 8*flow_pad[n,c,h-1+di,w-1+dj]
//
// R5: final. Single launch of the R3 kernel (R4's double-launch was a
// measurement instrument: marginal kernel cost = 245.8-221.3 = 24.6 us).
// Kernel runs at ~7.6 TB/s effective (186 MB traffic / 24.6 us) — above the
// 6.3 TB/s achievable HBM ceiling because the 151 MB mask is Infinity-Cache
// resident after the harness's restore copy. Remaining dur_us (~197 us) is
// harness re-poison/restore cost (576 MiB fillBufferAligned @ ~87 us in
// rocprof top-5), outside kernel control. This is the memory roofline.

#define N_ 8
#define H_ 64
#define W_ 128
#define HW_ (H_ * W_)

__global__ __launch_bounds__(256, 4) void flow_up_kernel(
    const float* __restrict__ flow,
    const float* __restrict__ mask,
    float* __restrict__ out)
{
    const int bid = blockIdx.x;
    const int a = bid & 7;
    const int h = (bid >> 3) & (H_ - 1);
    const int n = bid >> 9;
    const int t = threadIdx.x;
    const int b = t & 7;            // lane-minor: stores coalesce in 32B groups
    const int w4 = (t >> 3) << 2;   // 0,4,...,124

    // Halo rows r[c][di][j] = 8*flow_pad[n,c,h-1+di,w4-1+j], j=0..5, zero-padded.
    // Redundant across the 8 b-lanes per wq -> broadcast loads, L1-resident.
    float r0[3][6], r1[3][6];
    const float* __restrict__ f0 = flow + (n * 2 + 0) * HW_;
    const float* __restrict__ f1 = flow + (n * 2 + 1) * HW_;
#pragma unroll
    for (int di = 0; di < 3; ++di) {
        const int hr = h - 1 + di;
        const int hc = min(max(hr, 0), H_ - 1);
        const bool hin = (hr >= 0) && (hr < H_);
#pragma unroll
        for (int j = 0; j < 6; ++j) {
            const int wr = w4 - 1 + j;
            const int wc = min(max(wr, 0), W_ - 1);
            const float sc = (hin && wr >= 0 && wr < W_) ? 8.0f : 0.0f;
            r0[di][j] = f0[hc * W_ + wc] * sc;
            r1[di][j] = f1[hc * W_ + wc] * sc;
        }
    }

    // mask float4 pointer at (n, a*8+b, h, w4); k stride = 64*HW_ floats = 16*HW_ float4
    const float4* __restrict__ mp =
        (const float4*)(mask + (n * 576 + a * 8 + b) * HW_ + h * W_ + w4);

    float ss[4] = {0.f, 0.f, 0.f, 0.f};
    float o0[4] = {0.f, 0.f, 0.f, 0.f};
    float o1[4] = {0.f, 0.f, 0.f, 0.f};
#pragma unroll
    for (int k = 0; k < 9; ++k) {
        const int di = k / 3, dj = k % 3;      // compile-time (unrolled)
        const float4 m = mp[k * 16 * HW_];
        const float e0 = __expf(m.x), e1 = __expf(m.y),
                    e2 = __expf(m.z), e3 = __expf(m.w);
        ss[0] += e0; o0[0] += e0 * r0[di][dj + 0]; o1[0] += e0 * r1[di][dj + 0];
        ss[1] += e1; o0[1] += e1 * r0[di][dj + 1]; o1[1] += e1 * r1[di][dj + 1];
        ss[2] += e2; o0[2] += e2 * r0[di][dj + 2]; o1[2] += e2 * r1[di][dj + 2];
        ss[3] += e3; o0[3] += e3 * r0[di][dj + 3]; o1[3] += e3 * r1[di][dj + 3];
    }

    // out[n,c, 8h+a, 8*(w4+wi)+b]: lanes (b minor) pack 32B runs; wi=0..3
    // fills the 128B-strided gaps -> L2 write-combines to full lines.
    const int y = h * 8 + a;
    float* __restrict__ q0 = out + ((n * 2 + 0) * (8 * H_) + y) * (8 * W_) + 8 * w4 + b;
    float* __restrict__ q1 = out + ((n * 2 + 1) * (8 * H_) + y) * (8 * W_) + 8 * w4 + b;
#pragma unroll
    for (int wi = 0; wi < 4; ++wi) {
        const float inv = __builtin_amdgcn_rcpf(ss[wi]);  // threshold 0.54, 1-ulp ok
        q0[8 * wi] = o0[wi] * inv;
        q1[8 * wi] = o1[wi] * inv;
    }
}

extern "C" void kernel_launch(void* const* d_in, const int* in_sizes, int n_in,
                              void* d_out, int out_size, void* d_ws, size_t ws_size,
                              hipStream_t stream) {
    const float* flow = (const float*)d_in[0];
    const float* mask = (const float*)d_in[1];
    float* out = (float*)d_out;

    const int grid = N_ * H_ * 8;   // 4096 blocks, one per (n, h, a)
    flow_up_kernel<<<grid, 256, 0, stream>>>(flow, mask, out);
}